// Round 5
// baseline (12.150 us; speedup 1.0000x reference)
//
#include <hip/hip_runtime.h>

// CenterLoss reduced form:
//   loss = (1/B) * sum_i clip(||x_i||^2 + ||centers[y_i]||^2, 1e-12, 1e12)
//          + (C-1) * 1e-12        // clip floor on the B*(C-1) zero entries
//
// x: [16384,128] f32, centers: [10000,128] f32, y: [16384] int32.
// One wave (64 lanes) per row: lane l loads float2 at col 2l of the x-row and
// of the gathered center-row (both 512 B coalesced), shuffle-tree reduce,
// accumulate per-wave in double, per-block partial -> deterministic final
// tree reduction (no atomics => bit-stable across graph replays).

#define DIM 128
#define BATCH 16384
#define NUM_CLASSES 10000
#define MAIN_BLOCKS 1024   // 4 waves/block -> 4096 waves -> 4 rows per wave

__global__ __launch_bounds__(256) void centerloss_main(
    const float* __restrict__ x,
    const float* __restrict__ centers,
    const int* __restrict__ y,
    double* __restrict__ partials)
{
    const int lane = threadIdx.x & 63;
    const int wib  = threadIdx.x >> 6;               // wave in block [0,4)
    const int gwave = blockIdx.x * 4 + wib;
    const int nwaves = gridDim.x * 4;

    double acc = 0.0;
    for (int row = gwave; row < BATCH; row += nwaves) {
        // ||x_row||^2 : 64 lanes x float2 = 128 floats
        const float2 xv = *reinterpret_cast<const float2*>(x + (size_t)row * DIM + lane * 2);
        float s = xv.x * xv.x + xv.y * xv.y;

        // ||centers[y[row]]||^2 gathered row (same coalesced pattern)
        const int cls = y[row];
        const float2 cv = *reinterpret_cast<const float2*>(centers + (size_t)cls * DIM + lane * 2);
        float c = cv.x * cv.x + cv.y * cv.y;

        #pragma unroll
        for (int off = 32; off > 0; off >>= 1) {
            s += __shfl_down(s, off, 64);
            c += __shfl_down(c, off, 64);
        }
        if (lane == 0) {
            double dv = (double)s + (double)c;                 // d1 + d2 (f32 sums, like ref)
            dv = fmin(fmax(dv, 1e-12), 1e12);                  // clip (no-op in practice)
            acc += dv;
        }
    }

    __shared__ double lds[4];
    if (lane == 0) lds[wib] = acc;
    __syncthreads();
    if (threadIdx.x == 0)
        partials[blockIdx.x] = (lds[0] + lds[1]) + (lds[2] + lds[3]);
}

__global__ __launch_bounds__(256) void centerloss_final(
    const double* __restrict__ partials, float* __restrict__ out)
{
    __shared__ double lds[256];
    double s = 0.0;
    // fixed order: deterministic
    for (int i = threadIdx.x; i < MAIN_BLOCKS; i += 256) s += partials[i];
    lds[threadIdx.x] = s;
    __syncthreads();
    #pragma unroll
    for (int off = 128; off > 0; off >>= 1) {
        if (threadIdx.x < off) lds[threadIdx.x] += lds[threadIdx.x + off];
        __syncthreads();
    }
    if (threadIdx.x == 0) {
        double loss = lds[0] / (double)BATCH
                    + (double)(NUM_CLASSES - 1) * 1e-12;       // clip floor of zero entries
        out[0] = (float)loss;
    }
}

extern "C" void kernel_launch(void* const* d_in, const int* in_sizes, int n_in,
                              void* d_out, int out_size, void* d_ws, size_t ws_size,
                              hipStream_t stream)
{
    const float* x       = (const float*)d_in[0];
    const float* centers = (const float*)d_in[1];
    const int*   y       = (const int*)d_in[2];
    float*       out     = (float*)d_out;
    double*      partials = (double*)d_ws;           // MAIN_BLOCKS doubles = 8 KiB

    centerloss_main<<<MAIN_BLOCKS, 256, 0, stream>>>(x, centers, y, partials);
    centerloss_final<<<1, 256, 0, stream>>>(partials, out);
}